// Round 1
// baseline (5635.292 us; speedup 1.0000x reference)
//
#include <hip/hip_runtime.h>
#include <stdint.h>

#define HID   1024
#define TSEQ  256
#define BATCH 256
#define NWG   256

typedef __attribute__((ext_vector_type(8)))  short bf16x8;
typedef __attribute__((ext_vector_type(16))) float f32x16;

// float -> bf16 bits, round-to-nearest-even
__device__ __forceinline__ short f2bf(float f) {
  uint32_t u = __float_as_uint(f);
  u += 0x7fffu + ((u >> 16) & 1u);
  return (short)(u >> 16);
}

// Persistent LSTM kernel: 256 WGs (one per CU), grid barrier per timestep.
// WG(bi,hi): batch rows [bi*64, bi*64+64), hidden units [hi*16, hi*16+16).
// Gates tile per step: [M=64 batch x N=64 gate-rows], K=1024 via
// mfma_f32_32x32x16_bf16 with the W_hh slice held entirely in registers.
__global__ __launch_bounds__(256, 1) void lstm_persist(
    const float* __restrict__ x,      // [B][T]
    const float* __restrict__ W_ih,   // [4H]
    const float* __restrict__ b_ih,   // [4H]
    const float* __restrict__ W_hh,   // [4H][H]
    const float* __restrict__ b_hh,   // [4H]
    const float* __restrict__ W_out,  // [H]
    int*   __restrict__ flags,        // [NWG]      (zeroed)
    short* __restrict__ hbuf,         // [2][B][H]  bf16 bits (zeroed)
    float* __restrict__ out_acc)      // [B][T]     (zeroed)
{
  __shared__ __align__(16) short lds_h[2][64 * 128];  // 32 KB: h chunk dbuf
  __shared__ float lds_gates[64][68];                 // 17.4 KB
  __shared__ float lds_x[64];

  const int tid  = threadIdx.x;
  const int lane = tid & 63;
  const int wid  = tid >> 6;   // 4 waves
  const int wm   = wid >> 1;   // wave row-half  (0,1) -> rows wm*32..+32
  const int wn   = wid & 1;    // wave col-half  (0,1) -> cols wn*32..+32

  const int bx  = blockIdx.x;
  const int xcd = bx & 7;      // XCD = blockIdx % 8 (round-robin)
  const int jj  = bx >> 3;
  const int bi  = xcd >> 1;    // batch slice constant per XCD -> L2 locality
  const int hi  = (xcd & 1) * 32 + jj;
  const int b0  = bi * 64;
  const int u0  = hi * 16;

  // ---- W_hh slice -> register-resident B fragments (bf16) ----
  // B-frag (32x32x16): lane holds B[k=(lane>>5)*8+e][col=lane&31]
  bf16x8 breg[64];
  {
    const int n  = wn * 32 + (lane & 31);  // gate-col 0..63: [i f g o] x 16 units
    const int g  = n >> 4;
    const int uu = n & 15;
    const float* wrow = W_hh + (size_t)(g * HID + u0 + uu) * HID;
    const int koff = (lane >> 5) * 8;
#pragma unroll
    for (int kf = 0; kf < 64; ++kf) {
      bf16x8 v;
#pragma unroll
      for (int e = 0; e < 8; ++e) v[e] = f2bf(wrow[kf * 16 + koff + e]);
      breg[kf] = v;
    }
  }

  // ---- per-thread elementwise constants; thread -> (unit u, 4 rows) ----
  const int u  = tid & 15;
  const int rg = tid >> 4;
  float wih[4], bias[4];
#pragma unroll
  for (int g = 0; g < 4; ++g) {
    wih[g]  = W_ih[g * HID + u0 + u];
    bias[g] = b_ih[g * HID + u0 + u] + b_hh[g * HID + u0 + u];
  }
  const float wout = W_out[u0 + u];
  float cst[4] = {0.f, 0.f, 0.f, 0.f};

  const int arow = wm * 32 + (lane & 31);  // A row this lane reads
  const int scb  = (lane & 15) << 4;       // staging byte col 0..240

  for (int t = 0; t < TSEQ; ++t) {
    const int cur = t & 1;
    const short* __restrict__ hsrc = hbuf + (size_t)cur * (BATCH * HID);
    short* __restrict__ hdst = hbuf + (size_t)(cur ^ 1) * (BATCH * HID);

    if (tid < 64) lds_x[tid] = x[(b0 + tid) * TSEQ + t];

    f32x16 acc;
#pragma unroll
    for (int e = 0; e < 16; ++e) acc[e] = 0.f;

    bf16x8 streg[4];
    // stage chunk c: 64 rows x 128 elems (16 KB); wave moves 4x1KB slices.
    // LDS write XOR-swizzled (byte ^= (row&15)<<4) so mfma A-reads are
    // bank-conflict-free; same XOR applied on read (both-sides swizzle).
    auto stage_load = [&](int c) {
#pragma unroll
      for (int i = 0; i < 4; ++i) {
        int srow = wid * 16 + i * 4 + (lane >> 4);
        streg[i] = *(const bf16x8*)(hsrc + (size_t)(b0 + srow) * HID +
                                    c * 128 + (scb >> 1));
      }
    };
    auto stage_write = [&](int bufi) {
#pragma unroll
      for (int i = 0; i < 4; ++i) {
        int srow = wid * 16 + i * 4 + (lane >> 4);
        int byt  = srow * 256 + (scb ^ ((srow & 15) << 4));
        *(bf16x8*)((char*)&lds_h[bufi][0] + byt) = streg[i];
      }
    };

    stage_load(0);
    stage_write(0);

#pragma unroll
    for (int c = 0; c < 8; ++c) {
      __syncthreads();                       // chunk c visible; prev readers done
      if (c < 7) stage_load(c + 1);          // issue next-chunk global loads early
      const char* abase = (const char*)&lds_h[c & 1][0];
#pragma unroll
      for (int kk = 0; kk < 8; ++kk) {
        int cb = kk * 32 + ((lane >> 5) << 4);
        bf16x8 a = *(const bf16x8*)(abase + arow * 256 +
                                    (cb ^ ((arow & 15) << 4)));
        acc = __builtin_amdgcn_mfma_f32_32x32x16_bf16(a, breg[c * 8 + kk],
                                                      acc, 0, 0, 0);
      }
      if (c < 7) stage_write((c + 1) & 1);   // write-late after compute (T14-ish)
    }

    // ---- gates -> LDS (32x32 C layout: col=lane&31, row=(r&3)+8*(r>>2)+4*(lane>>5))
#pragma unroll
    for (int r = 0; r < 16; ++r) {
      int row = wm * 32 + (r & 3) + ((r >> 2) << 3) + ((lane >> 5) << 2);
      lds_gates[row][wn * 32 + (lane & 31)] = acc[r];
    }
    __syncthreads();

    // ---- elementwise LSTM cell update + output partial ----
#pragma unroll
    for (int r = 0; r < 4; ++r) {
      int row  = rg * 4 + r;
      float xv = lds_x[row];
      float gi = lds_gates[row][u]      + xv * wih[0] + bias[0];
      float gf = lds_gates[row][16 + u] + xv * wih[1] + bias[1];
      float gg = lds_gates[row][32 + u] + xv * wih[2] + bias[2];
      float go = lds_gates[row][48 + u] + xv * wih[3] + bias[3];
      float si = 1.f / (1.f + __expf(-gi));
      float sf = 1.f / (1.f + __expf(-gf));
      float tg = 1.f - 2.f / (__expf(2.f * gg) + 1.f);  // tanh, inf-safe
      float so = 1.f / (1.f + __expf(-go));
      float cc = sf * cst[r] + si * tg;
      cst[r]   = cc;
      float th = 1.f - 2.f / (__expf(2.f * cc) + 1.f);
      float hh = so * th;
      hdst[(size_t)(b0 + row) * HID + u0 + u] = f2bf(hh);
      // out[b][t] partial: reduce over the 16 units held by lanes u=0..15
      float contrib = hh * wout;
      contrib += __shfl_xor(contrib, 1);
      contrib += __shfl_xor(contrib, 2);
      contrib += __shfl_xor(contrib, 4);
      contrib += __shfl_xor(contrib, 8);
      if (u == 0) atomicAdd(&out_acc[(size_t)(b0 + row) * TSEQ + t], contrib);
    }

    // ---- grid barrier (release/acquire via __threadfence; monotonic flags) ----
    if (t < TSEQ - 1) {
      __syncthreads();                 // all waves' h stores drained (vmcnt 0)
      if (wid == 0) {
        __threadfence();               // release: writeback L2 -> LLC
        if (lane == 0) {
          __hip_atomic_store(&flags[bx], t + 1, __ATOMIC_RELAXED,
                             __HIP_MEMORY_SCOPE_AGENT);
        }
        const int tv = t + 1;
        int spins = 0, ok;
        do {
          int a0 = __hip_atomic_load(&flags[lane],       __ATOMIC_RELAXED, __HIP_MEMORY_SCOPE_AGENT);
          int a1 = __hip_atomic_load(&flags[lane +  64], __ATOMIC_RELAXED, __HIP_MEMORY_SCOPE_AGENT);
          int a2 = __hip_atomic_load(&flags[lane + 128], __ATOMIC_RELAXED, __HIP_MEMORY_SCOPE_AGENT);
          int a3 = __hip_atomic_load(&flags[lane + 192], __ATOMIC_RELAXED, __HIP_MEMORY_SCOPE_AGENT);
          ok = (a0 >= tv) && (a1 >= tv) && (a2 >= tv) && (a3 >= tv);
        } while (!__all(ok) && ++spins < (1 << 15));   // bailout beats deadlock
        __threadfence();               // acquire: invalidate L1/L2 (cross-XCD)
      }
      __syncthreads();
    }
  }
}

__global__ void finalize_out(const float* __restrict__ out_acc,
                             const float* __restrict__ b_out,
                             float* __restrict__ out) {
  int i = blockIdx.x * 256 + threadIdx.x;
  out[i] = out_acc[i] + b_out[0];
}

extern "C" void kernel_launch(void* const* d_in, const int* in_sizes, int n_in,
                              void* d_out, int out_size, void* d_ws, size_t ws_size,
                              hipStream_t stream) {
  const float* x     = (const float*)d_in[0];
  const float* W_ih  = (const float*)d_in[1];
  const float* b_ih  = (const float*)d_in[2];
  const float* W_hh  = (const float*)d_in[3];
  const float* b_hh  = (const float*)d_in[4];
  const float* W_out = (const float*)d_in[5];
  const float* b_out = (const float*)d_in[6];

  char*  ws      = (char*)d_ws;
  int*   flags   = (int*)ws;                                   // 1 KB
  short* hbuf    = (short*)(ws + 4096);                        // 1 MB
  float* out_acc = (float*)(ws + 4096 + 2 * BATCH * HID * 2);  // 256 KB

  size_t clear = 4096 + (size_t)2 * BATCH * HID * 2 + (size_t)BATCH * TSEQ * 4;
  hipMemsetAsync(d_ws, 0, clear, stream);  // zero flags, h0, out accumulator

  hipLaunchKernelGGL(lstm_persist, dim3(NWG), dim3(256), 0, stream,
                     x, W_ih, b_ih, W_hh, b_hh, W_out, flags, hbuf, out_acc);
  hipLaunchKernelGGL(finalize_out, dim3(BATCH * TSEQ / 256), dim3(256), 0, stream,
                     out_acc, b_out, (float*)d_out);
}

// Round 3
// 4975.686 us; speedup vs baseline: 1.1326x; 1.1326x over previous
//
#include <hip/hip_runtime.h>
#include <stdint.h>

#define HID   1024
#define TSEQ  256
#define BATCH 256
#define NWG   256

typedef __attribute__((ext_vector_type(8)))  short bf16x8;
typedef __attribute__((ext_vector_type(16))) float f32x16;
typedef __attribute__((ext_vector_type(4)))  int   i32x4;

// float -> bf16 bits, round-to-nearest-even
__device__ __forceinline__ short f2bf(float f) {
  uint32_t u = __float_as_uint(f);
  u += 0x7fffu + ((u >> 16) & 1u);
  return (short)(u >> 16);
}

// async 16B global->LDS (linear dest: wave-uniform base + lane*16)
__device__ __forceinline__ void glds16(const void* g, void* l) {
  __builtin_amdgcn_global_load_lds(
      (const __attribute__((address_space(1))) void*)g,
      (__attribute__((address_space(3))) void*)l, 16, 0, 0);
}

// h exchange tile layout (per dbuf half, per group bi): [chunk c 0..7][row 0..63][256B]
// byte-in-chunk-row for unit u (local k): (2*(u&127)) with 16B-block index XOR (row&15)
// -> global image IS the swizzled LDS image; global_load_lds copies it linearly.

// ds_read of B-frag (h): lane needs h[row_l][kk*16 + hi_l*8 .. +8]
#define DSRD(kk) (*(const bf16x8*)(lds_h + (((kk) >> 3) << 14) + rowoff + \
                   (((((kk) & 7) * 2 + hi_l) ^ rxor) << 4)))

#define STEP_K(kk) do { bf16x8 bb = DSRD(kk); \
    if ((kk) & 1) acc1 = __builtin_amdgcn_mfma_f32_32x32x16_bf16(breg[(kk)], bb, acc1, 0, 0, 0); \
    else          acc0 = __builtin_amdgcn_mfma_f32_32x32x16_bf16(breg[(kk)], bb, acc0, 0, 0, 0); \
  } while (0)

// counted wait (T4): chunk cc ready after its 4 glds done; x-load is newest (+1)
#define CHUNK(cc, NN) \
  asm volatile("s_waitcnt vmcnt(" #NN ")" ::: "memory"); \
  __builtin_amdgcn_s_barrier(); \
  asm volatile("" ::: "memory"); \
  STEP_K(cc * 8 + 0); STEP_K(cc * 8 + 1); STEP_K(cc * 8 + 2); STEP_K(cc * 8 + 3); \
  STEP_K(cc * 8 + 4); STEP_K(cc * 8 + 5); STEP_K(cc * 8 + 6); STEP_K(cc * 8 + 7);

__global__ __launch_bounds__(256, 1) void lstm_persist(
    const float* __restrict__ x,      // [B][T]
    const float* __restrict__ W_ih,   // [4H]
    const float* __restrict__ b_ih,   // [4H]
    const float* __restrict__ W_hh,   // [4H][H]
    const float* __restrict__ b_hh,   // [4H]
    const float* __restrict__ W_out,  // [H]
    int*   __restrict__ flags,        // [NWG]  zeroed
    char*  __restrict__ hbuf8,        // [2][4 groups][8][64][256] bytes, half0 zeroed
    float* __restrict__ part)         // [4*64][T][64] fp32 partial outputs
{
  __shared__ __align__(16) char lds_h[131072];  // 128 KB h tile (swizzled image)
  __shared__ float lds_po[2][64];

  const int tid  = threadIdx.x;
  const int lane = tid & 63;
  const int wid  = tid >> 6;   // 4 waves
  const int wm   = wid >> 1;   // gate-dim half: units wm*8..+8 of this WG's 16
  const int wn   = wid & 1;    // batch half:    rows wn*32..+32

  const int bx  = blockIdx.x;
  const int xcd = bx & 7;           // blockIdx%8 -> XCD (locality heuristic only)
  const int jj  = bx >> 3;
  const int bi  = xcd >> 1;         // batch-slice group 0..3 (2 XCDs/group)
  const int hi  = (xcd & 1) * 32 + jj;  // hidden slice 0..63
  const int b0  = bi * 64;
  const int u0  = hi * 16;

  const int nl   = lane & 31;
  const int hi_l = lane >> 5;
  const int row_l  = wn * 32 + nl;      // this lane's batch row (local 0..63)
  const int browg  = b0 + row_l;
  const int rowoff = row_l * 256;
  const int rxor   = row_l & 15;

  // ---- A-operand: W_hh rows for gate-cols n = wm*32 + nl, mapping n=(4*uu+g) ----
  // A-frag 32x32x16: lane holds A[row=n_local][k=(lane>>5)*8+e]
  bf16x8 breg[64];
  {
    const int n  = wm * 32 + nl;
    const int g  = n & 3;
    const int uu = n >> 2;            // wm*8 + (nl>>2)
    const float* wrow = W_hh + (size_t)(g * HID + u0 + uu) * HID;
    const int koff = hi_l * 8;
#pragma unroll
    for (int kf = 0; kf < 64; ++kf) {
      bf16x8 v;
#pragma unroll
      for (int e = 0; e < 8; ++e) v[e] = f2bf(wrow[kf * 16 + koff + e]);
      breg[kf] = v;
    }
  }

  // ---- per-lane elementwise constants: 4 unit-quads, unit uu(q)=wm*8+2q+hi_l ----
  float biasr[16], wihr[16], woutr[4], cst[4];
#pragma unroll
  for (int r = 0; r < 16; ++r) {
    int g   = r & 3;
    int uur = wm * 8 + 2 * (r >> 2) + hi_l;
    int idx = g * HID + u0 + uur;
    biasr[r] = b_ih[idx] + b_hh[idx];
    wihr[r]  = W_ih[idx];
  }
#pragma unroll
  for (int q = 0; q < 4; ++q) {
    woutr[q] = W_out[u0 + wm * 8 + 2 * q + hi_l];
    cst[q] = 0.f;
  }

  // h-store address pieces (lane<32 stores 16B = units u0+wm*8..+8 for its row)
  const int c_s = hi >> 3;                 // chunk of this WG's units
  const int B1  = 2 * (hi & 7) + wm;       // 16B block index before swizzle
  const size_t hoff = ((size_t)c_s << 14) + (size_t)rowoff + (size_t)((B1 ^ rxor) << 4);

  const int tv_base = 2 * bi;

  for (int t = 0; t < TSEQ; ++t) {
    const int cur = t & 1;
    const char* srcb = hbuf8 + (size_t)(cur * 4 + bi) * 131072 +
                       (size_t)wid * 4096 + (size_t)lane * 16;
    char* dstb = lds_h + wid * 4096;

    // ---- issue ALL staging loads (32 x 16B per wave), then x ----
#pragma unroll
    for (int c = 0; c < 8; ++c) {
#pragma unroll
      for (int i = 0; i < 4; ++i)
        glds16(srcb + c * 16384 + i * 1024, dstb + c * 16384 + i * 1024);
    }
    asm volatile("" ::: "memory");
    const float xv = x[(size_t)browg * TSEQ + t];
    asm volatile("" ::: "memory");

    f32x16 acc0, acc1;
#pragma unroll
    for (int e = 0; e < 16; ++e) { acc0[e] = 0.f; acc1[e] = 0.f; }

    // ---- K loop: per-chunk counted vmcnt + raw barrier, 8 MFMA each ----
    CHUNK(0, 29) CHUNK(1, 25) CHUNK(2, 21) CHUNK(3, 17)
    CHUNK(4, 13) CHUNK(5, 9)  CHUNK(6, 5)  CHUNK(7, 1)

    // ---- fully in-register LSTM cell update (4 units/lane) ----
    unsigned short hbv[4];
    float po = 0.f;
#pragma unroll
    for (int q = 0; q < 4; ++q) {
      float gi = acc0[4 * q + 0] + acc1[4 * q + 0] + xv * wihr[4 * q + 0] + biasr[4 * q + 0];
      float gf = acc0[4 * q + 1] + acc1[4 * q + 1] + xv * wihr[4 * q + 1] + biasr[4 * q + 1];
      float gg = acc0[4 * q + 2] + acc1[4 * q + 2] + xv * wihr[4 * q + 2] + biasr[4 * q + 2];
      float go = acc0[4 * q + 3] + acc1[4 * q + 3] + xv * wihr[4 * q + 3] + biasr[4 * q + 3];
      float si = 1.f / (1.f + __expf(-gi));
      float sf = 1.f / (1.f + __expf(-gf));
      float tg = 1.f - 2.f / (__expf(2.f * gg) + 1.f);
      float so = 1.f / (1.f + __expf(-go));
      float cc2 = sf * cst[q] + si * tg;
      cst[q] = cc2;
      float th = 1.f - 2.f / (__expf(2.f * cc2) + 1.f);
      float hv = so * th;
      hbv[q] = (unsigned short)f2bf(hv);
      po += hv * woutr[q];
    }
    po += __shfl_xor(po, 32);   // + partner lane's 4 units -> 8-unit row sum

    // pack h: interleave even(hi_l=0)/odd(hi_l=1) units -> one 16B store
    unsigned a0p = (unsigned)hbv[0] | ((unsigned)hbv[1] << 16);
    unsigned a1p = (unsigned)hbv[2] | ((unsigned)hbv[3] << 16);
    unsigned pa0 = __shfl_xor(a0p, 32);
    unsigned pa1 = __shfl_xor(a1p, 32);
    if (hi_l == 0) {
      i32x4 w;
      w[0] = (int)((a0p & 0xffffu) | (pa0 << 16));
      w[1] = (int)((a0p >> 16)     | (pa0 & 0xffff0000u));
      w[2] = (int)((a1p & 0xffffu) | (pa1 << 16));
      w[3] = (int)((a1p >> 16)     | (pa1 & 0xffff0000u));
      *(i32x4*)(hbuf8 + (size_t)((cur ^ 1) * 4 + bi) * 131072 + hoff) = w;
      lds_po[wm][row_l] = po;
    }

    __syncthreads();   // drains h stores (per-wave vmcnt0) + po visible

    if (wid == 2 || wid == 3) {      // overlap with wave0's barrier work
      if (lane < 32) {
        int r2 = (wid - 2) * 32 + lane;
        part[(((size_t)(bi * 64 + hi)) * TSEQ + t) * 64 + r2] =
            lds_po[0][r2] + lds_po[1][r2];
      }
    }

    // ---- per-group grid barrier (64 WGs, monotonic flags) ----
    if (t < TSEQ - 1) {
      if (wid == 0) {
        __threadfence();             // release: L2 writeback (cross-XCD visible)
        if (lane == 0)
          __hip_atomic_store(&flags[bx], t + 1, __ATOMIC_RELAXED,
                             __HIP_MEMORY_SCOPE_AGENT);
        const int tv = t + 1;
        const int mem = ((lane >> 1) << 3) + tv_base + (lane & 1);
        int spins = 0, ok;
        do {
          int a = __hip_atomic_load(&flags[mem], __ATOMIC_RELAXED,
                                    __HIP_MEMORY_SCOPE_AGENT);
          ok = (a >= tv);
        } while (!__all(ok) && ++spins < (1 << 16));  // bailout beats deadlock
        __threadfence();             // acquire: invalidate for fresh h reads
      }
      __syncthreads();
    }
  }
}

__global__ void finalize_out(const float* __restrict__ part,
                             const float* __restrict__ b_out,
                             float* __restrict__ out) {
  int idx = blockIdx.x * 256 + threadIdx.x;  // = b*TSEQ + t
  int b = idx >> 8, t = idx & 255;
  int bi = b >> 6, row = b & 63;
  float s = b_out[0];
  const float* p = part + (((size_t)bi * 64) * TSEQ + t) * 64 + row;
#pragma unroll 4
  for (int h = 0; h < 64; ++h) s += p[(size_t)h * TSEQ * 64];
  out[idx] = s;
}

extern "C" void kernel_launch(void* const* d_in, const int* in_sizes, int n_in,
                              void* d_out, int out_size, void* d_ws, size_t ws_size,
                              hipStream_t stream) {
  const float* x     = (const float*)d_in[0];
  const float* W_ih  = (const float*)d_in[1];
  const float* b_ih  = (const float*)d_in[2];
  const float* W_hh  = (const float*)d_in[3];
  const float* b_hh  = (const float*)d_in[4];
  const float* W_out = (const float*)d_in[5];
  const float* b_out = (const float*)d_in[6];

  char*  ws    = (char*)d_ws;
  int*   flags = (int*)ws;                         // 1 KB (+pad to 4 KB)
  char*  hbuf8 = ws + 4096;                        // 2 * 4 * 128 KB = 1 MB
  float* part  = (float*)(ws + 4096 + 1048576);    // 4*64*256*64*4 = 16.8 MB

  // zero flags + h(t=0) buffer half
  hipMemsetAsync(d_ws, 0, 4096 + 524288, stream);

  hipLaunchKernelGGL(lstm_persist, dim3(NWG), dim3(256), 0, stream,
                     x, W_ih, b_ih, W_hh, b_hh, W_out, flags, hbuf8, part);
  hipLaunchKernelGGL(finalize_out, dim3(BATCH * TSEQ / 256), dim3(256), 0, stream,
                     part, b_out, (float*)d_out);
}

// Round 6
// 3718.593 us; speedup vs baseline: 1.5154x; 1.3381x over previous
//
#include <hip/hip_runtime.h>
#include <stdint.h>

#define HID   1024
#define TSEQ  256
#define BATCH 256
#define NGRP  8     // 8 groups (nominally one per XCD under round-robin dispatch)
#define WPG   64    // WGs per group
#define NWG   512
#define ROWS  32    // batch rows per group

typedef short bf16x8 __attribute__((ext_vector_type(8)));
typedef float f32x16 __attribute__((ext_vector_type(16)));
typedef float f32x4  __attribute__((ext_vector_type(4)));

// float -> bf16 bits, round-to-nearest-even
__device__ __forceinline__ short f2bf(float f) {
  uint32_t u = __float_as_uint(f);
  u += 0x7fffu + ((u >> 16) & 1u);
  return (short)(u >> 16);
}

// LDS h tile: [32 rows][2048B]; 16B-block index XOR (row&15) (swizzle lives
// ONLY on the LDS side: applied at ds_write AND at ds_read; global is linear).
#define DSRD(kk) (*(const bf16x8*)(lds_h + nloff + \
                   ((((wk) * 64 + (kk) * 2 + hi_l) ^ rxor) << 4)))

#define MFMA(va, vb, vc) __builtin_amdgcn_mfma_f32_32x32x16_bf16(va, vb, vc, 0, 0, 0)

// All cross-WG traffic (himg, flags) uses agent-scope atomics: point-of-
// coherence routed by the memory model -- no fences, no cache ops, no
// guessed cpol bits. Ordering: atomic stores -> __syncthreads (vmcnt(0)
// drain, compiler-emitted) -> flag store; consumers: flag poll -> h loads.
__global__ __launch_bounds__(256, 2) void lstm_persist(
    const float* __restrict__ x,      // [B][T]
    const float* __restrict__ W_ih,   // [4H]
    const float* __restrict__ b_ih,   // [4H]
    const float* __restrict__ W_hh,   // [4H][H]
    const float* __restrict__ b_hh,   // [4H]
    const float* __restrict__ W_out,  // [H]
    int*      __restrict__ flags,     // [NGRP*WPG] zeroed
    uint64_t* __restrict__ himg,      // [2][NGRP][8192] u64 (64KB/half/group), zeroed
    float*    __restrict__ part)      // [NWG][TSEQ][ROWS] fp32 partials
{
  __shared__ __align__(16) char lds_h[65536];    // 64 KB swizzled h tile
  __shared__ float lds_exch[4][2][64][4];        // 8 KB acc exchange (wk1->wk0)
  __shared__ float lds_po[2][32];

  const int tid  = threadIdx.x;
  const int lane = tid & 63;
  const int wid  = tid >> 6;   // 4 waves
  const int wn2  = wid >> 1;   // gate-col half: cols wn2*32..+32 (units wn2*8..+8)
  const int wk   = wid & 1;    // K half: k in wk*512..+512
  const int nl   = lane & 31;
  const int hi_l = lane >> 5;

  const int bx   = blockIdx.x;
  const int g    = bx & 7;     // group (locality heuristic only; correctness-free)
  const int slot = bx >> 3;    // 0..63: hidden slice within group
  const int b0   = g * ROWS;
  const int u0   = slot * 16;

  // ---- A-operand: W_hh slice in registers (gate-col n = 4*unit+gate) ----
  // A-frag 32x32x16: lane holds A[row=nl][k = kf*16 + hi_l*8 + e]
  bf16x8 breg[32];
  {
    const int n  = wn2 * 32 + nl;
    const int gg = n & 3;
    const int uu = n >> 2;     // 0..15
    const float* wrow = W_hh + (size_t)(gg * HID + u0 + uu) * HID + wk * 512 + hi_l * 8;
#pragma unroll
    for (int kf = 0; kf < 32; ++kf) {
      bf16x8 v;
#pragma unroll
      for (int e = 0; e < 8; ++e) v[e] = f2bf(wrow[kf * 16 + e]);
      breg[kf] = v;
    }
  }

  // ---- per-lane elementwise constants (used by wk==0 waves) ----
  float biasr[16], wihr[16], woutr[4], cst[4];
#pragma unroll
  for (int r = 0; r < 16; ++r) {
    int gg  = r & 3;
    int uur = wn2 * 8 + 2 * (r >> 2) + hi_l;
    int idx = gg * HID + u0 + uur;
    biasr[r] = b_ih[idx] + b_hh[idx];
    wihr[r]  = W_ih[idx];
  }
#pragma unroll
  for (int q = 0; q < 4; ++q) {
    woutr[q] = W_out[u0 + wn2 * 8 + 2 * q + hi_l];
    cst[q] = 0.f;
  }

  const int nloff = nl * 2048;
  const int rxor  = nl & 15;
  const int b8s   = wid * 64 + lane;       // staging u64 index within a row
  const int sB1   = (slot * 2 + wn2) * 2;  // h-store u64 base within a row

  for (int t = 0; t < TSEQ; ++t) {
    const int cur = t & 1;
    const uint64_t* src = himg + (size_t)(cur * NGRP + g) * 8192;

    const float xv = x[(size_t)(b0 + nl) * TSEQ + t];

    // ---- stage h: coalesced agent-scope 8B loads + swizzled ds_write ----
#pragma unroll 8
    for (int i = 0; i < 32; ++i) {
      uint64_t v = __hip_atomic_load(src + i * 256 + b8s,
                                     __ATOMIC_RELAXED, __HIP_MEMORY_SCOPE_AGENT);
      *(uint64_t*)(lds_h + i * 2048 + (((b8s >> 1) ^ (i & 15)) << 4) +
                   (b8s & 1) * 8) = v;
    }
    __syncthreads();                       // tile staged (lgkmcnt+vmcnt drain)

    f32x16 acc0, acc1;
#pragma unroll
    for (int e = 0; e < 16; ++e) { acc0[e] = 0.f; acc1[e] = 0.f; }
#pragma unroll
    for (int kf = 0; kf < 32; kf += 2) {
      bf16x8 bb0 = DSRD(kf);
      bf16x8 bb1 = DSRD(kf + 1);
      acc0 = MFMA(breg[kf],     bb0, acc0);
      acc1 = MFMA(breg[kf + 1], bb1, acc1);
    }
    f32x16 accs = acc0 + acc1;

    if (wk == 1) {                         // send K-half to partner wave
#pragma unroll
      for (int q = 0; q < 4; ++q) {
        f32x4 v; v[0]=accs[4*q]; v[1]=accs[4*q+1]; v[2]=accs[4*q+2]; v[3]=accs[4*q+3];
        *(f32x4*)&lds_exch[q][wn2][lane][0] = v;
      }
    }
    __syncthreads();

    if (wk == 0) {
      unsigned short hbv[4];
      float po = 0.f;
#pragma unroll
      for (int q = 0; q < 4; ++q) {
        f32x4 ex = *(const f32x4*)&lds_exch[q][wn2][lane][0];
        float gi = accs[4*q+0] + ex[0] + xv * wihr[4*q+0] + biasr[4*q+0];
        float gf = accs[4*q+1] + ex[1] + xv * wihr[4*q+1] + biasr[4*q+1];
        float gg = accs[4*q+2] + ex[2] + xv * wihr[4*q+2] + biasr[4*q+2];
        float go = accs[4*q+3] + ex[3] + xv * wihr[4*q+3] + biasr[4*q+3];
        float si = 1.f / (1.f + __expf(-gi));
        float sf = 1.f / (1.f + __expf(-gf));
        float tg = 1.f - 2.f / (__expf(2.f * gg) + 1.f);
        float so = 1.f / (1.f + __expf(-go));
        float cc = sf * cst[q] + si * tg;
        cst[q] = cc;
        float th = 1.f - 2.f / (__expf(2.f * cc) + 1.f);
        float hv = so * th;
        hbv[q] = (unsigned short)f2bf(hv);
        po += hv * woutr[q];
      }
      po += __shfl_xor(po, 32);   // + partner lane's 4 units -> 8-unit row sum

      // pack h: interleave even(hi_l=0)/odd(hi_l=1) units -> 16B for this row
      unsigned a0p = (unsigned)hbv[0] | ((unsigned)hbv[1] << 16);
      unsigned a1p = (unsigned)hbv[2] | ((unsigned)hbv[3] << 16);
      unsigned pa0 = __shfl_xor(a0p, 32);
      unsigned pa1 = __shfl_xor(a1p, 32);
      if (hi_l == 0) {
        unsigned w0 = (a0p & 0xffffu) | (pa0 << 16);          // units 0,1
        unsigned w1 = (a0p >> 16)     | (pa0 & 0xffff0000u);  // units 2,3
        unsigned w2 = (a1p & 0xffffu) | (pa1 << 16);          // units 4,5
        unsigned w3 = (a1p >> 16)     | (pa1 & 0xffff0000u);  // units 6,7
        uint64_t* dst = himg + (size_t)((cur ^ 1) * NGRP + g) * 8192 +
                        nl * 256 + sB1;
        __hip_atomic_store(dst,     (uint64_t)w0 | ((uint64_t)w1 << 32),
                           __ATOMIC_RELAXED, __HIP_MEMORY_SCOPE_AGENT);
        __hip_atomic_store(dst + 1, (uint64_t)w2 | ((uint64_t)w3 << 32),
                           __ATOMIC_RELAXED, __HIP_MEMORY_SCOPE_AGENT);
        lds_po[wn2][nl] = po;
      }
    }

    __syncthreads();   // vmcnt(0) drain: h stores committed; po visible

    if (wid == 3 && lane < 32)             // overlap with wave0's flag work
      part[((size_t)(g * WPG + slot) * TSEQ + t) * ROWS + lane] =
          lds_po[0][lane] + lds_po[1][lane];

    // ---- per-group barrier: monotonic flags, agent-scope atomics ----
    if (t < TSEQ - 1) {
      if (wid == 0) {
        if (lane == 0)
          __hip_atomic_store(&flags[g * WPG + slot], t + 1,
                             __ATOMIC_RELAXED, __HIP_MEMORY_SCOPE_AGENT);
        const int tv = t + 1;
        const int* fp = flags + g * WPG + lane;     // 64 flags, 1/lane
        int spins = 0, ok;
        do {
          int a = __hip_atomic_load(fp, __ATOMIC_RELAXED,
                                    __HIP_MEMORY_SCOPE_AGENT);
          ok = (a >= tv);
        } while (!__all(ok) && ++spins < (1 << 16));  // bailout beats deadlock
      }
      __syncthreads();
    }
  }
}

__global__ void finalize_out(const float* __restrict__ part,
                             const float* __restrict__ b_out,
                             float* __restrict__ out) {
  int idx = blockIdx.x * 256 + threadIdx.x;  // = b*TSEQ + t
  int b = idx >> 8, t = idx & 255;
  int grp = b >> 5, row = b & 31;
  float s = b_out[0];
  const float* p = part + ((size_t)(grp * WPG) * TSEQ + t) * ROWS + row;
#pragma unroll 4
  for (int h = 0; h < WPG; ++h) s += p[(size_t)h * TSEQ * ROWS];
  out[idx] = s;
}

extern "C" void kernel_launch(void* const* d_in, const int* in_sizes, int n_in,
                              void* d_out, int out_size, void* d_ws, size_t ws_size,
                              hipStream_t stream) {
  const float* x     = (const float*)d_in[0];
  const float* W_ih  = (const float*)d_in[1];
  const float* b_ih  = (const float*)d_in[2];
  const float* W_hh  = (const float*)d_in[3];
  const float* b_hh  = (const float*)d_in[4];
  const float* W_out = (const float*)d_in[5];
  const float* b_out = (const float*)d_in[6];

  char*     ws    = (char*)d_ws;
  int*      flags = (int*)ws;                          // 2 KB (pad to 4 KB)
  uint64_t* himg  = (uint64_t*)(ws + 4096);            // 2*8*64KB = 1 MB
  float*    part  = (float*)(ws + 4096 + 1048576);     // 512*256*32*4 = 16.8 MB

  // zero flags + both h image halves (h0 = 0); re-done every launch (graph-safe)
  hipMemsetAsync(d_ws, 0, 4096 + 1048576, stream);

  hipLaunchKernelGGL(lstm_persist, dim3(NWG), dim3(256), 0, stream,
                     x, W_ih, b_ih, W_hh, b_hh, W_out, flags, himg, part);
  hipLaunchKernelGGL(finalize_out, dim3(BATCH * TSEQ / 256), dim3(256), 0, stream,
                     part, b_out, (float*)d_out);
}

// Round 7
// 3299.991 us; speedup vs baseline: 1.7077x; 1.1268x over previous
//
#include <hip/hip_runtime.h>
#include <stdint.h>

#define HID   1024
#define TSEQ  256
#define BATCH 256
#define NGRP  8     // 8 groups (nominally one per XCD under round-robin dispatch)
#define WPG   64    // WGs per group
#define NWG   512
#define ROWS  32    // batch rows per group

typedef short bf16x8 __attribute__((ext_vector_type(8)));
typedef float f32x16 __attribute__((ext_vector_type(16)));
typedef float f32x4  __attribute__((ext_vector_type(4)));
typedef int   i32x4  __attribute__((ext_vector_type(4)));

// float -> bf16 bits, round-to-nearest-even
__device__ __forceinline__ short f2bf(float f) {
  uint32_t u = __float_as_uint(f);
  u += 0x7fffu + ((u >> 16) & 1u);
  return (short)(u >> 16);
}

// LDS h tile: [32 rows][2048B]; 16B-block index XOR (row&15) (swizzle lives
// ONLY on the LDS side: applied at ds_write AND at ds_read; global is linear).
#define DSRD(kk) (*(const bf16x8*)(lds_h + nloff + \
                   ((((wk) * 64 + (kk) * 2 + hi_l) ^ rxor) << 4)))

#define MFMA(va, vb, vc) __builtin_amdgcn_mfma_f32_32x32x16_bf16(va, vb, vc, 0, 0, 0)

// Coherence protocol (proven in R6): cross-WG h/flag STORES and flag loads
// use agent-scope atomics. Staging h LOADS use global_load_dwordx4 with
// sc0+sc1 -- the gfx940-family system-scope load encoding (LLVM memory
// model), i.e. the same coherence routing as the atomics but 16B-wide and
// coalescing. Ordering: h stores -> __syncthreads (vmcnt0 drain) -> flag
// store; consumers: flag poll -> staged loads.
__global__ __launch_bounds__(256, 2) void lstm_persist(
    const float* __restrict__ x,      // [B][T]
    const float* __restrict__ W_ih,   // [4H]
    const float* __restrict__ b_ih,   // [4H]
    const float* __restrict__ W_hh,   // [4H][H]
    const float* __restrict__ b_hh,   // [4H]
    const float* __restrict__ W_out,  // [H]
    int*      __restrict__ flags,     // [NGRP*WPG] zeroed
    uint64_t* __restrict__ himg,      // [2][NGRP][8192] u64 (64KB/half/group), zeroed
    float*    __restrict__ part)      // [NWG][TSEQ][ROWS] fp32 partials
{
  __shared__ __align__(16) char lds_h[65536];    // 64 KB swizzled h tile
  __shared__ float lds_exch[4][2][64][4];        // 8 KB acc exchange (wk1->wk0)
  __shared__ float lds_po[2][32];

  const int tid  = threadIdx.x;
  const int lane = tid & 63;
  const int wid  = tid >> 6;   // 4 waves
  const int wn2  = wid >> 1;   // gate-col half: cols wn2*32..+32 (units wn2*8..+8)
  const int wk   = wid & 1;    // K half: k in wk*512..+512
  const int nl   = lane & 31;
  const int hi_l = lane >> 5;

  const int bx   = blockIdx.x;
  const int g    = bx & 7;     // group (locality heuristic only; correctness-free)
  const int slot = bx >> 3;    // 0..63: hidden slice within group
  const int b0   = g * ROWS;
  const int u0   = slot * 16;

  // ---- A-operand: W_hh slice in registers (gate-col n = 4*unit+gate) ----
  // A-frag 32x32x16: lane holds A[row=nl][k = kf*16 + hi_l*8 + e]
  bf16x8 breg[32];
  {
    const int n  = wn2 * 32 + nl;
    const int gg = n & 3;
    const int uu = n >> 2;     // 0..15
    const float* wrow = W_hh + (size_t)(gg * HID + u0 + uu) * HID + wk * 512 + hi_l * 8;
#pragma unroll
    for (int kf = 0; kf < 32; ++kf) {
      bf16x8 v;
#pragma unroll
      for (int e = 0; e < 8; ++e) v[e] = f2bf(wrow[kf * 16 + e]);
      breg[kf] = v;
    }
  }

  // ---- per-lane elementwise constants (used by wk==0 waves) ----
  float biasr[16], wihr[16], woutr[4], cst[4];
#pragma unroll
  for (int r = 0; r < 16; ++r) {
    int gg  = r & 3;
    int uur = wn2 * 8 + 2 * (r >> 2) + hi_l;
    int idx = gg * HID + u0 + uur;
    biasr[r] = b_ih[idx] + b_hh[idx];
    wihr[r]  = W_ih[idx];
  }
#pragma unroll
  for (int q = 0; q < 4; ++q) {
    woutr[q] = W_out[u0 + wn2 * 8 + 2 * q + hi_l];
    cst[q] = 0.f;
  }

  const int nloff = nl * 2048;
  const int rxor  = nl & 15;
  const int sB1   = (slot * 2 + wn2) * 2;  // h-store u64 base within a row
  const int rbase = tid >> 7;              // staging: LDS row parity
  const int colb  = tid & 127;             // staging: 16B block within row

  for (int t = 0; t < TSEQ; ++t) {
    const int cur = t & 1;
    const char* srcb = (const char*)(himg + (size_t)(cur * NGRP + g) * 8192) +
                       tid * 16;

    const float xv = x[(size_t)(b0 + nl) * TSEQ + t];

    // ---- stage h: 16B coherent loads (sc0 sc1) + swizzled ds_write ----
    i32x4 sv[16];
#pragma unroll
    for (int i = 0; i < 16; ++i) {
      asm volatile("global_load_dwordx4 %0, %1, off sc0 sc1"
                   : "=v"(sv[i]) : "v"(srcb + (size_t)i * 4096) : "memory");
    }
    asm volatile("s_waitcnt vmcnt(0)" ::: "memory");
#pragma unroll
    for (int i = 0; i < 16; ++i) {
      int row = i * 2 + rbase;
      *(i32x4*)(lds_h + row * 2048 + ((colb ^ (row & 15)) << 4)) = sv[i];
    }
    __syncthreads();                       // tile staged (lgkm drain)

    f32x16 acc0, acc1;
#pragma unroll
    for (int e = 0; e < 16; ++e) { acc0[e] = 0.f; acc1[e] = 0.f; }
#pragma unroll
    for (int kf = 0; kf < 32; kf += 2) {
      bf16x8 bb0 = DSRD(kf);
      bf16x8 bb1 = DSRD(kf + 1);
      acc0 = MFMA(breg[kf],     bb0, acc0);
      acc1 = MFMA(breg[kf + 1], bb1, acc1);
    }
    f32x16 accs = acc0 + acc1;

    if (wk == 1) {                         // send K-half to partner wave
#pragma unroll
      for (int q = 0; q < 4; ++q) {
        f32x4 v; v[0]=accs[4*q]; v[1]=accs[4*q+1]; v[2]=accs[4*q+2]; v[3]=accs[4*q+3];
        *(f32x4*)&lds_exch[q][wn2][lane][0] = v;
      }
    }
    __syncthreads();

    if (wk == 0) {
      unsigned short hbv[4];
      float po = 0.f;
#pragma unroll
      for (int q = 0; q < 4; ++q) {
        f32x4 ex = *(const f32x4*)&lds_exch[q][wn2][lane][0];
        float gi = accs[4*q+0] + ex[0] + xv * wihr[4*q+0] + biasr[4*q+0];
        float gf = accs[4*q+1] + ex[1] + xv * wihr[4*q+1] + biasr[4*q+1];
        float gg = accs[4*q+2] + ex[2] + xv * wihr[4*q+2] + biasr[4*q+2];
        float go = accs[4*q+3] + ex[3] + xv * wihr[4*q+3] + biasr[4*q+3];
        float si = 1.f / (1.f + __expf(-gi));
        float sf = 1.f / (1.f + __expf(-gf));
        float tg = 1.f - 2.f / (__expf(2.f * gg) + 1.f);
        float so = 1.f / (1.f + __expf(-go));
        float cc = sf * cst[q] + si * tg;
        cst[q] = cc;
        float th = 1.f - 2.f / (__expf(2.f * cc) + 1.f);
        float hv = so * th;
        hbv[q] = (unsigned short)f2bf(hv);
        po += hv * woutr[q];
      }
      po += __shfl_xor(po, 32);   // + partner lane's 4 units -> 8-unit row sum

      // pack h: interleave even(hi_l=0)/odd(hi_l=1) units -> 16B for this row
      unsigned a0p = (unsigned)hbv[0] | ((unsigned)hbv[1] << 16);
      unsigned a1p = (unsigned)hbv[2] | ((unsigned)hbv[3] << 16);
      unsigned pa0 = __shfl_xor(a0p, 32);
      unsigned pa1 = __shfl_xor(a1p, 32);
      if (hi_l == 0) {
        unsigned w0 = (a0p & 0xffffu) | (pa0 << 16);          // units 0,1
        unsigned w1 = (a0p >> 16)     | (pa0 & 0xffff0000u);  // units 2,3
        unsigned w2 = (a1p & 0xffffu) | (pa1 << 16);          // units 4,5
        unsigned w3 = (a1p >> 16)     | (pa1 & 0xffff0000u);  // units 6,7
        uint64_t* dst = himg + (size_t)((cur ^ 1) * NGRP + g) * 8192 +
                        nl * 256 + sB1;
        __hip_atomic_store(dst,     (uint64_t)w0 | ((uint64_t)w1 << 32),
                           __ATOMIC_RELAXED, __HIP_MEMORY_SCOPE_AGENT);
        __hip_atomic_store(dst + 1, (uint64_t)w2 | ((uint64_t)w3 << 32),
                           __ATOMIC_RELAXED, __HIP_MEMORY_SCOPE_AGENT);
        lds_po[wn2][nl] = po;
      }
    }

    __syncthreads();   // vmcnt(0) drain: h stores committed; po visible

    if (wid == 3 && lane < 32)             // overlap with wave0's flag work
      part[((size_t)(g * WPG + slot) * TSEQ + t) * ROWS + lane] =
          lds_po[0][lane] + lds_po[1][lane];

    // ---- per-group barrier: monotonic flags, agent-scope atomics ----
    if (t < TSEQ - 1) {
      if (wid == 0) {
        if (lane == 0)
          __hip_atomic_store(&flags[g * WPG + slot], t + 1,
                             __ATOMIC_RELAXED, __HIP_MEMORY_SCOPE_AGENT);
        const int tv = t + 1;
        const int* fp = flags + g * WPG + lane;     // 64 flags, 1/lane
        int spins = 0, ok;
        do {
          int a = __hip_atomic_load(fp, __ATOMIC_RELAXED,
                                    __HIP_MEMORY_SCOPE_AGENT);
          ok = (a >= tv);
        } while (!__all(ok) && ++spins < (1 << 16));  // bailout beats deadlock
      }
      __syncthreads();
    }
  }
}

__global__ void finalize_out(const float* __restrict__ part,
                             const float* __restrict__ b_out,
                             float* __restrict__ out) {
  int idx = blockIdx.x * 256 + threadIdx.x;  // = b*TSEQ + t
  int b = idx >> 8, t = idx & 255;
  int grp = b >> 5, row = b & 31;
  float s = b_out[0];
  const float* p = part + ((size_t)(grp * WPG) * TSEQ + t) * ROWS + row;
#pragma unroll 4
  for (int h = 0; h < WPG; ++h) s += p[(size_t)h * TSEQ * ROWS];
  out[idx] = s;
}

extern "C" void kernel_launch(void* const* d_in, const int* in_sizes, int n_in,
                              void* d_out, int out_size, void* d_ws, size_t ws_size,
                              hipStream_t stream) {
  const float* x     = (const float*)d_in[0];
  const float* W_ih  = (const float*)d_in[1];
  const float* b_ih  = (const float*)d_in[2];
  const float* W_hh  = (const float*)d_in[3];
  const float* b_hh  = (const float*)d_in[4];
  const float* W_out = (const float*)d_in[5];
  const float* b_out = (const float*)d_in[6];

  char*     ws    = (char*)d_ws;
  int*      flags = (int*)ws;                          // 2 KB (pad to 4 KB)
  uint64_t* himg  = (uint64_t*)(ws + 4096);            // 2*8*64KB = 1 MB
  float*    part  = (float*)(ws + 4096 + 1048576);     // 512*256*32*4 = 16.8 MB

  // zero flags + both h image halves (h0 = 0); re-done every launch (graph-safe)
  hipMemsetAsync(d_ws, 0, 4096 + 1048576, stream);

  hipLaunchKernelGGL(lstm_persist, dim3(NWG), dim3(256), 0, stream,
                     x, W_ih, b_ih, W_hh, b_hh, W_out, flags, himg, part);
  hipLaunchKernelGGL(finalize_out, dim3(BATCH * TSEQ / 256), dim3(256), 0, stream,
                     part, b_out, (float*)d_out);
}

// Round 8
// 1874.762 us; speedup vs baseline: 3.0059x; 1.7602x over previous
//
#include <hip/hip_runtime.h>
#include <stdint.h>

#define HID   1024
#define TSEQ  256
#define BATCH 256
#define NGRP  8     // 8 groups (nominally one per XCD under round-robin dispatch)
#define WPG   32    // WGs per group (one per CU of that XCD)
#define NWG   256
#define ROWS  32    // batch rows per group
#define UPW   32    // hidden units per WG

typedef short bf16x8 __attribute__((ext_vector_type(8)));
typedef float f32x16 __attribute__((ext_vector_type(16)));
typedef float f32x4  __attribute__((ext_vector_type(4)));
typedef int   i32x4  __attribute__((ext_vector_type(4)));

// float -> bf16 bits, round-to-nearest-even
__device__ __forceinline__ short f2bf(float f) {
  uint32_t u = __float_as_uint(f);
  u += 0x7fffu + ((u >> 16) & 1u);
  return (short)(u >> 16);
}

// LDS h tile: [32 rows][2048B]; 16B-block index XOR (row&15) (swizzle lives
// ONLY on the LDS side: applied at ds_write AND at ds_read; global is linear).
#define DSRD(kk) (*(const bf16x8*)(lds_h + nloff + \
                   ((((kk) * 2 + hi_l) ^ rxor) << 4)))

#define MFMA(va, vb, vc) __builtin_amdgcn_mfma_f32_32x32x16_bf16(va, vb, vc, 0, 0, 0)

// Coherence protocol (proven R6/R7): h stores = agent-scope atomics; staged
// h loads = global_load_dwordx4 sc0 sc1 (system-scope load encoding).
// Barrier: per-WG atomicAdd on ctr[g] AFTER the __syncthreads drain (the
// add carries the release); consumers poll ctr[g] >= WPG*(t+1) with ONE
// lane per WG on ONE address -> no 64-wide poll storm, no separate flag hop.
__global__ __launch_bounds__(256, 1) void lstm_persist(
    const float* __restrict__ x,      // [B][T]
    const float* __restrict__ W_ih,   // [4H]
    const float* __restrict__ b_ih,   // [4H]
    const float* __restrict__ W_hh,   // [4H][H]
    const float* __restrict__ b_hh,   // [4H]
    const float* __restrict__ W_out,  // [H]
    int*      __restrict__ ctr,       // [NGRP] arrival counters, zeroed
    uint64_t* __restrict__ himg,      // [2][NGRP][8192] u64 (64KB/half/group), zeroed
    float*    __restrict__ part)      // [NWG][TSEQ][ROWS] fp32 partials
{
  __shared__ __align__(16) char lds_h[65536];    // 64 KB swizzled h tile
  __shared__ float lds_po[4][32];

  const int tid  = threadIdx.x;
  const int lane = tid & 63;
  const int wid  = tid >> 6;   // 4 waves; wave owns units wid*8..+8 (full K)
  const int nl   = lane & 31;
  const int hi_l = lane >> 5;

  const int bx   = blockIdx.x;
  const int g    = bx & 7;     // group (locality heuristic only; correctness-free)
  const int slot = bx >> 3;    // 0..31: unit slice within group
  const int b0   = g * ROWS;
  const int u0   = slot * UPW; // 32 units per WG

  // ---- A-operand: W_hh slice in registers (gate-col n = 4*unit_local+gate) ----
  // Wave's 32 gate-cols cover its 8 units; A-frag lane holds A[row=nl][k=kf*16+hi_l*8+e]
  bf16x8 breg[64];
  {
    const int gg = nl & 3;                 // gate
    const int uu = nl >> 2;                // unit_local 0..7
    const float* wrow = W_hh + (size_t)(gg * HID + u0 + wid * 8 + uu) * HID + hi_l * 8;
#pragma unroll
    for (int kf = 0; kf < 64; ++kf) {
      bf16x8 v;
#pragma unroll
      for (int e = 0; e < 8; ++e) v[e] = f2bf(wrow[kf * 16 + e]);
      breg[kf] = v;
    }
  }

  // ---- per-lane elementwise constants ----
  float biasr[16], wihr[16], woutr[4], cst[4];
#pragma unroll
  for (int r = 0; r < 16; ++r) {
    int gg  = r & 3;
    int uur = wid * 8 + 2 * (r >> 2) + hi_l;
    int idx = gg * HID + u0 + uur;
    biasr[r] = b_ih[idx] + b_hh[idx];
    wihr[r]  = W_ih[idx];
  }
#pragma unroll
  for (int q = 0; q < 4; ++q) {
    woutr[q] = W_out[u0 + wid * 8 + 2 * q + hi_l];
    cst[q] = 0.f;
  }

  const int nloff = nl * 2048;
  const int rxor  = nl & 15;
  const int sB1   = slot * 8 + wid * 2;    // h-store u64 base within a row
  const int rbase = tid >> 7;              // staging: LDS row parity
  const int colb  = tid & 127;             // staging: 16B block within row

  for (int t = 0; t < TSEQ; ++t) {
    const int cur = t & 1;
    const char* srcb = (const char*)(himg + (size_t)(cur * NGRP + g) * 8192) +
                       tid * 16;

    const float xv = x[(size_t)(b0 + nl) * TSEQ + t];

    // ---- stage h: 16B coherent loads (sc0 sc1) + swizzled ds_write ----
    i32x4 sv[16];
#pragma unroll
    for (int i = 0; i < 16; ++i) {
      asm volatile("global_load_dwordx4 %0, %1, off sc0 sc1"
                   : "=v"(sv[i]) : "v"(srcb + (size_t)i * 4096) : "memory");
    }
    asm volatile("s_waitcnt vmcnt(0)" ::: "memory");
#pragma unroll
    for (int i = 0; i < 16; ++i) {
      int row = i * 2 + rbase;
      *(i32x4*)(lds_h + row * 2048 + ((colb ^ (row & 15)) << 4)) = sv[i];
    }
    __syncthreads();                       // tile staged (lgkm drain)

    f32x16 acc0, acc1;
#pragma unroll
    for (int e = 0; e < 16; ++e) { acc0[e] = 0.f; acc1[e] = 0.f; }
#pragma unroll
    for (int kf = 0; kf < 64; kf += 2) {
      bf16x8 bb0 = DSRD(kf);
      bf16x8 bb1 = DSRD(kf + 1);
      acc0 = MFMA(breg[kf],     bb0, acc0);
      acc1 = MFMA(breg[kf + 1], bb1, acc1);
    }
    f32x16 accs = acc0 + acc1;

    // ---- fully in-register LSTM cell update (4 units/lane; all waves) ----
    unsigned short hbv[4];
    float po = 0.f;
#pragma unroll
    for (int q = 0; q < 4; ++q) {
      float gi = accs[4*q+0] + xv * wihr[4*q+0] + biasr[4*q+0];
      float gf = accs[4*q+1] + xv * wihr[4*q+1] + biasr[4*q+1];
      float gg = accs[4*q+2] + xv * wihr[4*q+2] + biasr[4*q+2];
      float go = accs[4*q+3] + xv * wihr[4*q+3] + biasr[4*q+3];
      float si = 1.f / (1.f + __expf(-gi));
      float sf = 1.f / (1.f + __expf(-gf));
      float tg = 1.f - 2.f / (__expf(2.f * gg) + 1.f);
      float so = 1.f / (1.f + __expf(-go));
      float cc = sf * cst[q] + si * tg;
      cst[q] = cc;
      float th = 1.f - 2.f / (__expf(2.f * cc) + 1.f);
      float hv = so * th;
      hbv[q] = (unsigned short)f2bf(hv);
      po += hv * woutr[q];
    }
    po += __shfl_xor(po, 32);   // + partner lane's 4 units -> 8-unit row sum

    // pack h: interleave even(hi_l=0)/odd(hi_l=1) units -> 16B for this row
    unsigned a0p = (unsigned)hbv[0] | ((unsigned)hbv[1] << 16);
    unsigned a1p = (unsigned)hbv[2] | ((unsigned)hbv[3] << 16);
    unsigned pa0 = __shfl_xor(a0p, 32);
    unsigned pa1 = __shfl_xor(a1p, 32);
    if (hi_l == 0) {
      unsigned w0 = (a0p & 0xffffu) | (pa0 << 16);          // units 0,1
      unsigned w1 = (a0p >> 16)     | (pa0 & 0xffff0000u);  // units 2,3
      unsigned w2 = (a1p & 0xffffu) | (pa1 << 16);          // units 4,5
      unsigned w3 = (a1p >> 16)     | (pa1 & 0xffff0000u);  // units 6,7
      uint64_t* dst = himg + (size_t)((cur ^ 1) * NGRP + g) * 8192 +
                      nl * 256 + sB1;
      __hip_atomic_store(dst,     (uint64_t)w0 | ((uint64_t)w1 << 32),
                         __ATOMIC_RELAXED, __HIP_MEMORY_SCOPE_AGENT);
      __hip_atomic_store(dst + 1, (uint64_t)w2 | ((uint64_t)w3 << 32),
                         __ATOMIC_RELAXED, __HIP_MEMORY_SCOPE_AGENT);
      lds_po[wid][nl] = po;
    }

    __syncthreads();   // vmcnt(0) drain: h stores committed; po visible

    if (wid == 3 && lane < 32)             // overlap with lane0's barrier work
      part[((size_t)(g * WPG + slot) * TSEQ + t) * ROWS + lane] =
          lds_po[0][lane] + lds_po[1][lane] + lds_po[2][lane] + lds_po[3][lane];

    // ---- per-group barrier: single arrival counter, 1-lane poll ----
    if (t < TSEQ - 1) {
      if (tid == 0) {
        atomicAdd(&ctr[g], 1);             // release: ordered after drain above
        const int tv = WPG * (t + 1);
        int spins = 0, a;
        do {
          a = __hip_atomic_load(&ctr[g], __ATOMIC_RELAXED,
                                __HIP_MEMORY_SCOPE_AGENT);
        } while (a < tv && ++spins < (1 << 17));  // bailout beats deadlock
      }
      __syncthreads();
    }
  }
}

__global__ void finalize_out(const float* __restrict__ part,
                             const float* __restrict__ b_out,
                             float* __restrict__ out) {
  int idx = blockIdx.x * 256 + threadIdx.x;  // = b*TSEQ + t
  int b = idx >> 8, t = idx & 255;
  int grp = b >> 5, row = b & 31;
  float s = b_out[0];
  const float* p = part + ((size_t)(grp * WPG) * TSEQ + t) * ROWS + row;
#pragma unroll 4
  for (int h = 0; h < WPG; ++h) s += p[(size_t)h * TSEQ * ROWS];
  out[idx] = s;
}

extern "C" void kernel_launch(void* const* d_in, const int* in_sizes, int n_in,
                              void* d_out, int out_size, void* d_ws, size_t ws_size,
                              hipStream_t stream) {
  const float* x     = (const float*)d_in[0];
  const float* W_ih  = (const float*)d_in[1];
  const float* b_ih  = (const float*)d_in[2];
  const float* W_hh  = (const float*)d_in[3];
  const float* b_hh  = (const float*)d_in[4];
  const float* W_out = (const float*)d_in[5];
  const float* b_out = (const float*)d_in[6];

  char*     ws   = (char*)d_ws;
  int*      ctrp = (int*)ws;                           // 32 B (pad to 4 KB)
  uint64_t* himg = (uint64_t*)(ws + 4096);             // 2*8*64KB = 1 MB
  float*    part = (float*)(ws + 4096 + 1048576);      // 256*256*32*4 = 8.4 MB

  // zero counters + both h image halves (h0 = 0); re-done every launch
  hipMemsetAsync(d_ws, 0, 4096 + 1048576, stream);

  hipLaunchKernelGGL(lstm_persist, dim3(NWG), dim3(256), 0, stream,
                     x, W_ih, b_ih, W_hh, b_hh, W_out, ctrp, himg, part);
  hipLaunchKernelGGL(finalize_out, dim3(BATCH * TSEQ / 256), dim3(256), 0, stream,
                     part, b_out, (float*)d_out);
}